// Round 2
// baseline (5195.950 us; speedup 1.0000x reference)
//
#include <hip/hip_runtime.h>
#include <hip/hip_bf16.h>
#include <math.h>

// Problem constants (B=2, L=1024, D=1024, expand=2)
namespace {
constexpr int Bb = 2, Ll = 1024, Dd = 1024;
constexpr int NLAYER = 4, DSTATE = 16, DCONV = 4;
constexpr int Ee = 2 * Dd;                 // 2048
constexpr int DTRANK = (Dd + 15) / 16;     // 64
constexpr int XPROJ = DTRANK + 2 * DSTATE; // 96
constexpr float EPS = 1e-5f;
constexpr int ROWS = Bb * Ll;              // 2048
}

// Dual-dtype scalar load: inputs may be fp32 (per reference) or bf16
// (if the harness downcast). Flag detected at runtime on-device.
__device__ __forceinline__ float ldin(const void* p, size_t i, int isbf) {
    if (isbf) return __bfloat162float(((const __hip_bfloat16*)p)[i]);
    return ((const float*)p)[i];
}

// norm_f_w is all-ones: fp32 word0 = 0x3F800000, bf16 pair = 0x3F803F80.
__global__ void detect_kernel(const unsigned* __restrict__ nf, int* __restrict__ flag) {
    if (threadIdx.x == 0 && blockIdx.x == 0)
        *flag = (nf[0] == 0x3F800000u) ? 0 : 1;
}

// ---------------------------------------------------------------------------
// Fused residual add + RMSNorm.
// mode 0: layer0:  res = h_in;            hn = rmsnorm(res)*w
// mode 1: mid:     res = res + h_f;       hn = rmsnorm(res)*w
// mode 2: final:   v   = res + h_f;       out = rmsnorm(v)*w  (dtype per flag)
// One block per row (D=1024, 256 threads x 4 elems).
// ---------------------------------------------------------------------------
__global__ __launch_bounds__(256) void addnorm_kernel(
    const void* __restrict__ h_in, const float* __restrict__ h_f,
    float* __restrict__ res, const void* __restrict__ w, size_t w_off,
    float* __restrict__ hn_out, void* __restrict__ out, int mode,
    const int* __restrict__ flagp)
{
    const int isbf = *flagp;
    const int row = blockIdx.x;
    const int tid = threadIdx.x;
    const size_t base = (size_t)row * Dd;

    float vals[4];
    float ssum = 0.f;
#pragma unroll
    for (int i = 0; i < 4; i++) {
        const int d = tid + i * 256;
        float v;
        if (mode == 0) v = ldin(h_in, base + d, isbf);
        else           v = res[base + d] + h_f[base + d];
        vals[i] = v;
        ssum += v * v;
    }
#pragma unroll
    for (int off = 32; off > 0; off >>= 1) ssum += __shfl_down(ssum, off, 64);
    __shared__ float sred[4];
    if ((tid & 63) == 0) sred[tid >> 6] = ssum;
    __syncthreads();
    const float tot = sred[0] + sred[1] + sred[2] + sred[3];
    const float scale = rsqrtf(tot / (float)Dd + EPS);

#pragma unroll
    for (int i = 0; i < 4; i++) {
        const int d = tid + i * 256;
        const float v = vals[i];
        const float o = v * scale * ldin(w, w_off + d, isbf);
        if (mode == 2) {
            if (isbf) ((__hip_bfloat16*)out)[base + d] = __float2bfloat16(o);
            else      ((float*)out)[base + d] = o;
        } else {
            res[base + d] = v;
            hn_out[base + d] = o;
        }
    }
}

// ---------------------------------------------------------------------------
// Generic GEMM: C[M,N] = A[M,K] (fp32, row stride lda) * W[N,K]^T (flag dtype).
// epilogue 0: none; 1: softplus(x + bias[n]).
// 64x64 tile, BK=16, 256 threads, 4x4 register micro-tile.
// Requires: M % 64 == 0, K % 16 == 0. N bounds-checked.
// ---------------------------------------------------------------------------
#define GBM 64
#define GBN 64
#define GBK 16

__global__ __launch_bounds__(256) void gemm_kernel(
    const float* __restrict__ A, int lda,
    const void* __restrict__ W_base, size_t w_off,
    float* __restrict__ C, int M, int N, int K,
    const void* __restrict__ bias, size_t bias_off, int epilogue,
    const int* __restrict__ flagp)
{
    const int isbf = *flagp;
    __shared__ float As[GBK][GBM];
    __shared__ float Ws[GBK][GBN];

    const int tid = threadIdx.x;
    const int m0 = blockIdx.y * GBM;
    const int n0 = blockIdx.x * GBN;

    const int lrow = tid >> 2;        // 0..63
    const int lk   = (tid & 3) * 4;   // 0,4,8,12

    const int tm = (tid >> 4) * 4;    // 0..60
    const int tn = (tid & 15) * 4;    // 0..60

    float acc[4][4] = {};

    for (int k0 = 0; k0 < K; k0 += GBK) {
        // stage A tile (float4 per thread)
        {
            const float4 av = *(const float4*)(A + (size_t)(m0 + lrow) * lda + k0 + lk);
            As[lk + 0][lrow] = av.x;
            As[lk + 1][lrow] = av.y;
            As[lk + 2][lrow] = av.z;
            As[lk + 3][lrow] = av.w;
        }
        // stage W tile
        {
            const int n = n0 + lrow;
            float wv0 = 0.f, wv1 = 0.f, wv2 = 0.f, wv3 = 0.f;
            if (n < N) {
                const size_t eoff = w_off + (size_t)n * K + k0 + lk;
                if (isbf) {
                    const unsigned long long w4 =
                        *(const unsigned long long*)((const unsigned short*)W_base + eoff);
                    wv0 = __uint_as_float((unsigned)( w4        & 0xFFFFull) << 16);
                    wv1 = __uint_as_float((unsigned)((w4 >> 16) & 0xFFFFull) << 16);
                    wv2 = __uint_as_float((unsigned)((w4 >> 32) & 0xFFFFull) << 16);
                    wv3 = __uint_as_float((unsigned)((w4 >> 48) & 0xFFFFull) << 16);
                } else {
                    const float4 f = *(const float4*)((const float*)W_base + eoff);
                    wv0 = f.x; wv1 = f.y; wv2 = f.z; wv3 = f.w;
                }
            }
            Ws[lk + 0][lrow] = wv0;
            Ws[lk + 1][lrow] = wv1;
            Ws[lk + 2][lrow] = wv2;
            Ws[lk + 3][lrow] = wv3;
        }
        __syncthreads();
#pragma unroll
        for (int kk = 0; kk < GBK; kk++) {
            float a[4], b[4];
#pragma unroll
            for (int i = 0; i < 4; i++) a[i] = As[kk][tm + i];
#pragma unroll
            for (int j = 0; j < 4; j++) b[j] = Ws[kk][tn + j];
#pragma unroll
            for (int i = 0; i < 4; i++)
#pragma unroll
                for (int j = 0; j < 4; j++)
                    acc[i][j] = fmaf(a[i], b[j], acc[i][j]);
        }
        __syncthreads();
    }

#pragma unroll
    for (int i = 0; i < 4; i++) {
        const int m = m0 + tm + i;
#pragma unroll
        for (int j = 0; j < 4; j++) {
            const int n = n0 + tn + j;
            if (n < N) {
                float v = acc[i][j];
                if (epilogue == 1) {
                    v += ldin(bias, bias_off + n, isbf);
                    v = (v > 20.f) ? v : log1pf(expf(v));
                }
                C[(size_t)m * N + n] = v;
            }
        }
    }
}

// ---------------------------------------------------------------------------
// Causal depthwise conv (width 4) + bias + SiLU.
// ---------------------------------------------------------------------------
__global__ __launch_bounds__(256) void conv_kernel(
    const float* __restrict__ xz,
    const void* __restrict__ cw, size_t cw_off,
    const void* __restrict__ cb, size_t cb_off,
    float* __restrict__ u, const int* __restrict__ flagp)
{
    const int isbf = *flagp;
    const int idx = blockIdx.x * 256 + threadIdx.x; // over ROWS*E
    const int e = idx & (Ee - 1);
    const int bl = idx >> 11;
    const int l = bl & (Ll - 1);

    float acc = ldin(cb, cb_off + e, isbf);
#pragma unroll
    for (int k = 0; k < DCONV; k++) {
        const int ls = l - (DCONV - 1) + k;
        if (ls >= 0) {
            const float x = xz[(size_t)(bl - (DCONV - 1) + k) * (2 * Ee) + e];
            acc = fmaf(ldin(cw, cw_off + e * DCONV + k, isbf), x, acc);
        }
    }
    const float s = acc / (1.f + __expf(-acc));
    u[idx] = s;
}

// ---------------------------------------------------------------------------
// Selective scan: one thread per (b,e) channel; 16-state in registers.
// Fused output gating: y = (scan + u*D) * silu(z).
// ---------------------------------------------------------------------------
__global__ __launch_bounds__(256) void scan_kernel(
    const float* __restrict__ dt, const float* __restrict__ u,
    const float* __restrict__ xdb, const float* __restrict__ xz,
    const void* __restrict__ A_log, size_t al_off,
    const void* __restrict__ Dp, size_t dp_off,
    float* __restrict__ y, const int* __restrict__ flagp)
{
    const int isbf = *flagp;
    const int idx = blockIdx.x * 256 + threadIdx.x; // over B*E
    const int e = idx & (Ee - 1);
    const int b = idx >> 11;

    float A[DSTATE], st[DSTATE];
#pragma unroll
    for (int n = 0; n < DSTATE; n++) {
        A[n] = -__expf(ldin(A_log, al_off + e * DSTATE + n, isbf));
        st[n] = 0.f;
    }
    const float De = ldin(Dp, dp_off + e, isbf);

    for (int l = 0; l < Ll; l++) {
        const int bl = b * Ll + l;
        const float dt_t = dt[(size_t)bl * Ee + e];
        const float u_t  = u[(size_t)bl * Ee + e];
        const float du = dt_t * u_t;
        const float* bc = xdb + (size_t)bl * XPROJ;
        float ys = 0.f;
#pragma unroll
        for (int n = 0; n < DSTATE; n++) {
            const float dA = __expf(dt_t * A[n]);
            st[n] = fmaf(dA, st[n], du * bc[DTRANK + n]);
            ys = fmaf(st[n], bc[DTRANK + DSTATE + n], ys);
        }
        const float z = xz[(size_t)bl * (2 * Ee) + Ee + e];
        const float sz = z / (1.f + __expf(-z));
        y[(size_t)bl * Ee + e] = (ys + u_t * De) * sz;
    }
}

// ---------------------------------------------------------------------------
extern "C" void kernel_launch(void* const* d_in, const int* in_sizes, int n_in,
                              void* d_out, int out_size, void* d_ws, size_t ws_size,
                              hipStream_t stream)
{
    const void* hs    = d_in[0];
    const void* ipw   = d_in[1];
    const void* convw = d_in[2];
    const void* convb = d_in[3];
    const void* xpw   = d_in[4];
    const void* dtw   = d_in[5];
    const void* dtb   = d_in[6];
    const void* alog  = d_in[7];
    const void* dpar  = d_in[8];
    const void* opw   = d_in[9];
    const void* normw = d_in[10];
    const void* normf = d_in[11];

    // Workspace layout (fp32). First 64 floats: dtype flag + pad.
    int*   flag = (int*)d_ws;
    float* res = (float*)d_ws + 64;                 // ROWS*D
    float* hf  = res + (size_t)ROWS * Dd;           // ROWS*D
    float* xz  = hf  + (size_t)ROWS * Dd;           // ROWS*2E
    float* u   = xz  + (size_t)ROWS * 2 * Ee;       // ROWS*E
    float* dt  = u   + (size_t)ROWS * Ee;           // ROWS*E
    float* hny = dt  + (size_t)ROWS * Ee;           // ROWS*E (hn in first half, then y)
    float* xdb = hny + (size_t)ROWS * Ee;           // ROWS*XPROJ

    const size_t need_floats = 64 +
        (size_t)ROWS * Dd * 2 + (size_t)ROWS * 2 * Ee + (size_t)ROWS * Ee * 3 +
        (size_t)ROWS * XPROJ;
    if (need_floats * sizeof(float) > ws_size) return;

    float* hn = hny;
    float* y  = hny;

    detect_kernel<<<1, 64, 0, stream>>>((const unsigned*)normf, flag);

    for (int i = 0; i < NLAYER; i++) {
        // 1. residual add + prenorm
        addnorm_kernel<<<ROWS, 256, 0, stream>>>(
            hs, hf, res, normw, (size_t)i * Dd, hn, nullptr, i == 0 ? 0 : 1, flag);

        // 2. xz = hn @ in_proj^T   (2048 x 4096 x 1024)
        {
            dim3 g(2 * Ee / GBN, ROWS / GBM);
            gemm_kernel<<<g, 256, 0, stream>>>(
                hn, Dd, ipw, (size_t)i * 2 * Ee * Dd, xz, ROWS, 2 * Ee, Dd,
                nullptr, 0, 0, flag);
        }

        // 3. causal conv + silu -> u
        conv_kernel<<<ROWS * Ee / 256, 256, 0, stream>>>(
            xz, convw, (size_t)i * Ee * DCONV, convb, (size_t)i * Ee, u, flag);

        // 4. xdb = u @ x_proj^T    (2048 x 96 x 2048)
        {
            dim3 g((XPROJ + GBN - 1) / GBN, ROWS / GBM);
            gemm_kernel<<<g, 256, 0, stream>>>(
                u, Ee, xpw, (size_t)i * XPROJ * Ee, xdb, ROWS, XPROJ, Ee,
                nullptr, 0, 0, flag);
        }

        // 5. dt = softplus(xdb[:, :64] @ dt_proj^T + dtb)   (2048 x 2048 x 64)
        {
            dim3 g(Ee / GBN, ROWS / GBM);
            gemm_kernel<<<g, 256, 0, stream>>>(
                xdb, XPROJ, dtw, (size_t)i * Ee * DTRANK, dt, ROWS, Ee, DTRANK,
                dtb, (size_t)i * Ee, 1, flag);
        }

        // 6. selective scan (fused D-skip and silu(z) gate) -> y
        scan_kernel<<<Bb * Ee / 256, 256, 0, stream>>>(
            dt, u, xdb, xz, alog, (size_t)i * Ee * DSTATE,
            dpar, (size_t)i * Ee, y, flag);

        // 7. h = y @ out_proj^T    (2048 x 1024 x 2048)
        {
            dim3 g(Dd / GBN, ROWS / GBM);
            gemm_kernel<<<g, 256, 0, stream>>>(
                y, Ee, opw, (size_t)i * Dd * Ee, hf, ROWS, Dd, Ee,
                nullptr, 0, 0, flag);
        }
    }

    // final: out = rmsnorm(h + residual) -> dtype per flag
    addnorm_kernel<<<ROWS, 256, 0, stream>>>(
        nullptr, hf, res, normf, 0, nullptr, d_out, 2, flag);
}